// Round 1
// baseline (612.342 us; speedup 1.0000x reference)
//
#include <hip/hip_runtime.h>
#include <hip/hip_bf16.h>

// Fused attention block: x@Wqkv -> RoPE -> causal GQA flash attention -> @Wo
// bf16 MFMA compute everywhere (2% abs tolerance), f32 I/O.

typedef __attribute__((ext_vector_type(8))) short short8;   // 8 bf16 = 4 VGPR (MFMA A/B frag)
typedef __attribute__((ext_vector_type(4))) float f32x4;    // MFMA C/D frag

__device__ __forceinline__ unsigned short f2bfu(float f){
  unsigned u = __float_as_uint(f);
  u += 0x7FFFu + ((u >> 16) & 1u);      // RNE (no NaNs in this workload)
  return (unsigned short)(u >> 16);
}
__device__ __forceinline__ float bfu2f(unsigned short u){
  return __uint_as_float(((unsigned)u) << 16);
}

// ---------------- elementwise f32 -> bf16 ----------------
__global__ void convx_kernel(const float* __restrict__ x, unsigned short* __restrict__ xb, int n4){
  int i = blockIdx.x * blockDim.x + threadIdx.x;
  if (i >= n4) return;
  float4 v = reinterpret_cast<const float4*>(x)[i];
  ushort4 o;
  o.x = f2bfu(v.x); o.y = f2bfu(v.y); o.z = f2bfu(v.z); o.w = f2bfu(v.w);
  reinterpret_cast<ushort4*>(xb)[i] = o;
}

// ---------------- tiled transpose + convert: out[n][k] = (bf16)in[k][n] ----------------
__global__ void transpose_conv_kernel(const float* __restrict__ in, unsigned short* __restrict__ out,
                                      int Min, int Nin){
  __shared__ float t[32][33];
  int c0 = blockIdx.x * 32, r0 = blockIdx.y * 32;
  int tx = threadIdx.x, ty = threadIdx.y;   // 32 x 8
  #pragma unroll
  for (int i = ty; i < 32; i += 8) t[i][tx] = in[(size_t)(r0 + i) * Nin + c0 + tx];
  __syncthreads();
  #pragma unroll
  for (int i = ty; i < 32; i += 8) out[(size_t)(c0 + i) * Min + r0 + tx] = f2bfu(t[tx][i]);
}

// ---------------- m97-style bf16 GEMM: C[M][N] = A[M][K] * B^T[N][K] ----------------
template<bool OUTBF16>
__global__ __launch_bounds__(256) void gemm_bt_kernel(const unsigned short* __restrict__ A,
                                                      const unsigned short* __restrict__ B,
                                                      void* __restrict__ Cp,
                                                      int M, int N, int K){
  __shared__ unsigned short sA[128 * 32];
  __shared__ unsigned short sB[128 * 32];
  const int tid = threadIdx.x;
  const int l = tid & 63, w = tid >> 6;
  const int row0 = blockIdx.y * 128, col0 = blockIdx.x * 128;
  const int wr = w >> 1, wc = w & 1;

  // staging: each wave stages 2x 1KiB chunks of A and B per K-step (global_load_lds width 16)
  const unsigned short* Ap0 = A + (size_t)(row0 + w * 32 + (l >> 2)) * K + (l & 3) * 8;
  const unsigned short* Ap1 = Ap0 + (size_t)16 * K;
  const unsigned short* Bp0 = B + (size_t)(col0 + w * 32 + (l >> 2)) * K + (l & 3) * 8;
  const unsigned short* Bp1 = Bp0 + (size_t)16 * K;

  auto ldsA0 = (__attribute__((address_space(3))) void*)(&sA[w * 1024]);
  auto ldsA1 = (__attribute__((address_space(3))) void*)(&sA[w * 1024 + 512]);
  auto ldsB0 = (__attribute__((address_space(3))) void*)(&sB[w * 1024]);
  auto ldsB1 = (__attribute__((address_space(3))) void*)(&sB[w * 1024 + 512]);

  f32x4 acc[4][4] = {};

  const int kq = (l >> 4) * 8;
  const unsigned short* aRd[4];
  const unsigned short* bRd[4];
  #pragma unroll
  for (int m = 0; m < 4; m++) aRd[m] = &sA[(wr * 64 + m * 16 + (l & 15)) * 32 + kq];
  #pragma unroll
  for (int n = 0; n < 4; n++) bRd[n] = &sB[(wc * 64 + n * 16 + (l & 15)) * 32 + kq];

  for (int k0 = 0; k0 < K; k0 += 32){
    __builtin_amdgcn_global_load_lds((const __attribute__((address_space(1))) void*)(Ap0 + k0), ldsA0, 16, 0, 0);
    __builtin_amdgcn_global_load_lds((const __attribute__((address_space(1))) void*)(Ap1 + k0), ldsA1, 16, 0, 0);
    __builtin_amdgcn_global_load_lds((const __attribute__((address_space(1))) void*)(Bp0 + k0), ldsB0, 16, 0, 0);
    __builtin_amdgcn_global_load_lds((const __attribute__((address_space(1))) void*)(Bp1 + k0), ldsB1, 16, 0, 0);
    __syncthreads();   // compiler emits vmcnt(0) drain + barrier: LDS tiles ready
    short8 af[4], bf[4];
    #pragma unroll
    for (int m = 0; m < 4; m++) af[m] = *reinterpret_cast<const short8*>(aRd[m]);
    #pragma unroll
    for (int n = 0; n < 4; n++) bf[n] = *reinterpret_cast<const short8*>(bRd[n]);
    #pragma unroll
    for (int m = 0; m < 4; m++)
      #pragma unroll
      for (int n = 0; n < 4; n++)
        acc[m][n] = __builtin_amdgcn_mfma_f32_16x16x32_bf16(af[m], bf[n], acc[m][n], 0, 0, 0);
    __syncthreads();   // all waves done reading before next stage overwrites
  }

  const int orow = row0 + wr * 64 + ((l >> 4) << 2);
  const int ocol = col0 + wc * 64 + (l & 15);
  #pragma unroll
  for (int m = 0; m < 4; m++)
    #pragma unroll
    for (int n = 0; n < 4; n++)
      #pragma unroll
      for (int r = 0; r < 4; r++){
        size_t off = (size_t)(orow + m * 16 + r) * N + (ocol + n * 16);
        if (OUTBF16) ((unsigned short*)Cp)[off] = f2bfu(acc[m][n][r]);
        else         ((float*)Cp)[off] = acc[m][n][r];
      }
}

// ---------------- RoPE (interleaved pairs) on q (with softmax scale folded) and k ----------------
// qkv: bf16 [4096][3072] (q | k | v). Qo: [4096][2048]. Ko: [b][kvh][s][64].
__global__ void rope_kernel(const unsigned short* __restrict__ qkv, const float* __restrict__ cosb,
                            const float* __restrict__ sinb, unsigned short* __restrict__ Qo,
                            unsigned short* __restrict__ Ko){
  int idx = blockIdx.x * 256 + threadIdx.x;
  const int NQ = 4096 * 1024;   // q pairs
  if (idx < NQ){
    int m = idx >> 10, p = idx & 1023;
    int h = p >> 5, i = p & 31;
    int s = m & 2047;
    unsigned pr = *reinterpret_cast<const unsigned*>(qkv + (size_t)m * 3072 + h * 64 + 2 * i);
    float t0 = bfu2f((unsigned short)(pr & 0xFFFFu));
    float t1 = bfu2f((unsigned short)(pr >> 16));
    float c = cosb[s * 32 + i], sn = sinb[s * 32 + i];
    const float SC = 0.18033688011112042f;   // (1/8) * log2(e) -> exp2-domain softmax
    float o0 = (t0 * c - t1 * sn) * SC;
    float o1 = (t0 * sn + t1 * c) * SC;
    unsigned ow = (unsigned)f2bfu(o0) | ((unsigned)f2bfu(o1) << 16);
    *reinterpret_cast<unsigned*>(Qo + (size_t)m * 2048 + h * 64 + 2 * i) = ow;
  } else {
    int j = idx - NQ;   // k pairs: 4096*256 total (grid sized exactly)
    int m = j >> 8, p = j & 255;
    int kvh = p >> 5, i = p & 31;
    int s = m & 2047, b = m >> 11;
    unsigned pr = *reinterpret_cast<const unsigned*>(qkv + (size_t)m * 3072 + 2048 + kvh * 64 + 2 * i);
    float t0 = bfu2f((unsigned short)(pr & 0xFFFFu));
    float t1 = bfu2f((unsigned short)(pr >> 16));
    float c = cosb[s * 32 + i], sn = sinb[s * 32 + i];
    float o0 = t0 * c - t1 * sn;
    float o1 = t0 * sn + t1 * c;
    unsigned ow = (unsigned)f2bfu(o0) | ((unsigned)f2bfu(o1) << 16);
    *reinterpret_cast<unsigned*>(Ko + ((size_t)(b * 8 + kvh) * 2048 + s) * 64 + 2 * i) = ow;
  }
}

// ---------------- V transpose: v_t[b][kvh][d][s] from qkv cols [2560,3072) ----------------
__global__ void vtrans_kernel(const unsigned short* __restrict__ qkv, unsigned short* __restrict__ Vt){
  __shared__ float t[64][65];
  int bh = blockIdx.y;                   // 16 = b*8 + kvh
  int s0 = blockIdx.x * 64;
  int b = bh >> 3, kvh = bh & 7;
  int tid = threadIdx.x;
  #pragma unroll
  for (int it = 0; it < 16; it++){
    int id = it * 256 + tid;
    int sl = id >> 6, d = id & 63;
    unsigned short u = qkv[(size_t)(b * 2048 + s0 + sl) * 3072 + 2560 + kvh * 64 + d];
    t[sl][d] = bfu2f(u);
  }
  __syncthreads();
  #pragma unroll
  for (int it = 0; it < 16; it++){
    int id = it * 256 + tid;
    int dl = id >> 6, sl = id & 63;
    Vt[((size_t)(b * 8 + kvh) * 64 + dl) * 2048 + s0 + sl] = f2bfu(t[sl][dl]);
  }
}

// ---------------- causal GQA flash attention ----------------
// Q: [4096][2048] bf16 (pre-scaled). Kt: [b][kvh][s][64]. Vt: [b][kvh][d][s]. O: [4096][2048] bf16.
// 4 independent waves/block, 16 q-rows each, KB=64 kv tiles, online softmax in exp2 domain.
__global__ __launch_bounds__(256) void attn_kernel(const unsigned short* __restrict__ Q,
                                                   const unsigned short* __restrict__ Kt,
                                                   const unsigned short* __restrict__ Vt,
                                                   unsigned short* __restrict__ O){
  __shared__ unsigned short pl[4][16 * 64];   // per-wave P round-trip buffer
  const int tid = threadIdx.x;
  const int l = tid & 63, w = tid >> 6;
  const int qt = (int)gridDim.x - 1 - (int)blockIdx.x;   // big tiles dispatch first
  const int bh = blockIdx.y;
  const int b = bh >> 5, h = bh & 31, kvh = h >> 2;
  const int q0w = qt * 64 + w * 16;
  const int kq = (l >> 4) * 8;
  const int c16 = l & 15;

  const unsigned short* Kb = Kt + (size_t)(b * 8 + kvh) * 2048 * 64;
  const unsigned short* Vb = Vt + (size_t)(b * 8 + kvh) * 64 * 2048;

  const unsigned short* Qp = Q + ((size_t)(b * 2048 + q0w + c16)) * 2048 + h * 64 + kq;
  short8 aq0 = *reinterpret_cast<const short8*>(Qp);
  short8 aq1 = *reinterpret_cast<const short8*>(Qp + 32);

  f32x4 acc_o[4] = {};
  float m_run[4], l_run[4];
  #pragma unroll
  for (int r = 0; r < 4; r++){ m_run[r] = -1e30f; l_run[r] = 0.f; }

  unsigned short* myp = &pl[w][0];
  const int qlast = q0w + 15;
  for (int kv0 = 0; kv0 <= qlast; kv0 += 64){
    // ---- S = Q K^T (exp2 domain, scale pre-folded into Q) ----
    f32x4 s[4];
    #pragma unroll
    for (int kb = 0; kb < 4; kb++){
      const unsigned short* Kr = Kb + (size_t)(kv0 + kb * 16 + c16) * 64 + kq;
      short8 bk0 = *reinterpret_cast<const short8*>(Kr);
      short8 bk1 = *reinterpret_cast<const short8*>(Kr + 32);
      f32x4 z = {};
      z = __builtin_amdgcn_mfma_f32_16x16x32_bf16(aq0, bk0, z, 0, 0, 0);
      z = __builtin_amdgcn_mfma_f32_16x16x32_bf16(aq1, bk1, z, 0, 0, 0);
      s[kb] = z;
    }
    if (kv0 + 64 > q0w){   // diagonal tile(s): causal mask
      #pragma unroll
      for (int kb = 0; kb < 4; kb++){
        int kv = kv0 + kb * 16 + c16;
        #pragma unroll
        for (int r = 0; r < 4; r++){
          int qr = q0w + ((l >> 4) << 2) + r;
          if (kv > qr) s[kb][r] = -1e30f;
        }
      }
    }
    // ---- online softmax: rows live across 16 lanes (xor-butterfly 1,2,4,8) ----
    float tm[4];
    #pragma unroll
    for (int r = 0; r < 4; r++)
      tm[r] = fmaxf(fmaxf(s[0][r], s[1][r]), fmaxf(s[2][r], s[3][r]));
    #pragma unroll
    for (int d = 1; d < 16; d <<= 1){
      #pragma unroll
      for (int r = 0; r < 4; r++) tm[r] = fmaxf(tm[r], __shfl_xor(tm[r], d));
    }
    float al[4];
    #pragma unroll
    for (int r = 0; r < 4; r++){
      float mn = fmaxf(m_run[r], tm[r]);
      al[r] = exp2f(m_run[r] - mn);
      m_run[r] = mn;
    }
    float rs[4] = {0.f, 0.f, 0.f, 0.f};
    #pragma unroll
    for (int kb = 0; kb < 4; kb++)
      #pragma unroll
      for (int r = 0; r < 4; r++){
        float p = exp2f(s[kb][r] - m_run[r]);
        s[kb][r] = p;
        rs[r] += p;
      }
    #pragma unroll
    for (int d = 1; d < 16; d <<= 1){
      #pragma unroll
      for (int r = 0; r < 4; r++) rs[r] += __shfl_xor(rs[r], d);
    }
    #pragma unroll
    for (int r = 0; r < 4; r++) l_run[r] = l_run[r] * al[r] + rs[r];
    #pragma unroll
    for (int db = 0; db < 4; db++)
      #pragma unroll
      for (int r = 0; r < 4; r++) acc_o[db][r] *= al[r];

    // ---- P (D-frag layout) -> LDS -> A-frag layout; intra-wave, no barrier ----
    const int prow = (l >> 4) << 2;
    #pragma unroll
    for (int kb = 0; kb < 4; kb++)
      #pragma unroll
      for (int r = 0; r < 4; r++)
        myp[(prow + r) * 64 + kb * 16 + c16] = f2bfu(s[kb][r]);
    asm volatile("s_waitcnt lgkmcnt(0)" ::: "memory");
    __builtin_amdgcn_sched_barrier(0);
    short8 ap0 = *reinterpret_cast<const short8*>(myp + c16 * 64 + kq);
    short8 ap1 = *reinterpret_cast<const short8*>(myp + c16 * 64 + 32 + kq);

    // ---- O += P V ----
    #pragma unroll
    for (int db = 0; db < 4; db++){
      const unsigned short* Vr = Vb + (size_t)(db * 16 + c16) * 2048 + kv0 + kq;
      short8 bv0 = *reinterpret_cast<const short8*>(Vr);
      short8 bv1 = *reinterpret_cast<const short8*>(Vr + 32);
      acc_o[db] = __builtin_amdgcn_mfma_f32_16x16x32_bf16(ap0, bv0, acc_o[db], 0, 0, 0);
      acc_o[db] = __builtin_amdgcn_mfma_f32_16x16x32_bf16(ap1, bv1, acc_o[db], 0, 0, 0);
    }
  }

  float inv[4];
  #pragma unroll
  for (int r = 0; r < 4; r++) inv[r] = 1.0f / l_run[r];
  const int orow = q0w + ((l >> 4) << 2);
  #pragma unroll
  for (int db = 0; db < 4; db++)
    #pragma unroll
    for (int r = 0; r < 4; r++)
      O[((size_t)(b * 2048 + orow + r)) * 2048 + h * 64 + db * 16 + c16] = f2bfu(acc_o[db][r] * inv[r]);
}

extern "C" void kernel_launch(void* const* d_in, const int* in_sizes, int n_in,
                              void* d_out, int out_size, void* d_ws, size_t ws_size,
                              hipStream_t stream){
  (void)in_sizes; (void)n_in; (void)out_size; (void)ws_size;
  const float* x  = (const float*)d_in[0];
  const float* cb = (const float*)d_in[1];
  const float* sb = (const float*)d_in[2];
  const float* Wq = (const float*)d_in[3];
  const float* Wk = (const float*)d_in[4];
  const float* Wv = (const float*)d_in[5];
  const float* Wo = (const float*)d_in[6];
  float* out = (float*)d_out;
  char* ws = (char*)d_ws;

  // workspace layout (bytes), total 79,691,776:
  unsigned short* qkv = (unsigned short*)(ws + 0);           // [4096][3072] bf16 (25.2 MB)
  unsigned short* xb  = (unsigned short*)(ws + 25165824);    // [4096][2048] bf16; reused as attn-out
  unsigned short* wt  = (unsigned short*)(ws + 41943040);    // WqkvT [3072][2048]; later WoT [2048][2048]
  unsigned short* qb  = (unsigned short*)(ws + 54525952);    // roped q [4096][2048]
  unsigned short* kb  = (unsigned short*)(ws + 71303168);    // roped k [b][kvh][2048][64]
  unsigned short* vt  = (unsigned short*)(ws + 75497472);    // v^T [b][kvh][64][2048]

  dim3 tb(32, 8);
  convx_kernel<<<8192, 256, 0, stream>>>(x, xb, 2097152);
  transpose_conv_kernel<<<dim3(64, 64), tb, 0, stream>>>(Wq, wt, 2048, 2048);
  transpose_conv_kernel<<<dim3(16, 64), tb, 0, stream>>>(Wk, wt + (size_t)2048 * 2048, 2048, 512);
  transpose_conv_kernel<<<dim3(16, 64), tb, 0, stream>>>(Wv, wt + (size_t)2560 * 2048, 2048, 512);
  gemm_bt_kernel<true><<<dim3(24, 32), 256, 0, stream>>>(xb, wt, qkv, 4096, 3072, 2048);
  rope_kernel<<<20480, 256, 0, stream>>>(qkv, cb, sb, qb, kb);
  vtrans_kernel<<<dim3(32, 16), 256, 0, stream>>>(qkv, vt);
  transpose_conv_kernel<<<dim3(64, 64), tb, 0, stream>>>(Wo, wt, 2048, 2048);  // wt now = WoT
  attn_kernel<<<dim3(32, 64), 256, 0, stream>>>(qb, kb, vt, xb);               // xb now = attn features
  gemm_bt_kernel<false><<<dim3(16, 32), 256, 0, stream>>>(xb, wt, out, 4096, 2048, 2048);
}

// Round 2
// 343.276 us; speedup vs baseline: 1.7838x; 1.7838x over previous
//
#include <hip/hip_runtime.h>
#include <hip/hip_bf16.h>

// Fused attention block: x@Wqkv -> RoPE -> causal GQA flash attention -> @Wo
// bf16 MFMA compute everywhere (2% abs tolerance), f32 I/O.

typedef __attribute__((ext_vector_type(8))) short short8;   // 8 bf16 = 4 VGPR (MFMA A/B frag)
typedef __attribute__((ext_vector_type(4))) float f32x4;    // MFMA C/D frag

__device__ __forceinline__ unsigned short f2bfu(float f){
  unsigned u = __float_as_uint(f);
  u += 0x7FFFu + ((u >> 16) & 1u);      // RNE (no NaNs in this workload)
  return (unsigned short)(u >> 16);
}
__device__ __forceinline__ float bfu2f(unsigned short u){
  return __uint_as_float(((unsigned)u) << 16);
}
// swizzled element offset in a 64-col bf16 row: slot = 16B unit 0..7, XOR row&7
__device__ __forceinline__ int swz64(int row, int slot){
  return row * 64 + (((slot) ^ (row & 7)) << 3);
}

// ---------------- elementwise f32 -> bf16 ----------------
__global__ void convx_kernel(const float* __restrict__ x, unsigned short* __restrict__ xb, int n4){
  int i = blockIdx.x * blockDim.x + threadIdx.x;
  if (i >= n4) return;
  float4 v = reinterpret_cast<const float4*>(x)[i];
  ushort4 o;
  o.x = f2bfu(v.x); o.y = f2bfu(v.y); o.z = f2bfu(v.z); o.w = f2bfu(v.w);
  reinterpret_cast<ushort4*>(xb)[i] = o;
}

// ---------------- tiled transpose + convert: out[n][k] = (bf16)in[k][n] ----------------
__global__ void transpose_conv_kernel(const float* __restrict__ in, unsigned short* __restrict__ out,
                                      int Min, int Nin){
  __shared__ float t[32][33];
  int c0 = blockIdx.x * 32, r0 = blockIdx.y * 32;
  int tx = threadIdx.x, ty = threadIdx.y;   // 32 x 8
  #pragma unroll
  for (int i = ty; i < 32; i += 8) t[i][tx] = in[(size_t)(r0 + i) * Nin + c0 + tx];
  __syncthreads();
  #pragma unroll
  for (int i = ty; i < 32; i += 8) out[(size_t)(c0 + i) * Min + r0 + tx] = f2bfu(t[tx][i]);
}

// ---------------- m97-style bf16 GEMM: C[M][N] = A[M][K] * B^T[N][K] ----------------
template<bool OUTBF16>
__global__ __launch_bounds__(256) void gemm_bt_kernel(const unsigned short* __restrict__ A,
                                                      const unsigned short* __restrict__ B,
                                                      void* __restrict__ Cp,
                                                      int M, int N, int K){
  __shared__ unsigned short sA[128 * 32];
  __shared__ unsigned short sB[128 * 32];
  const int tid = threadIdx.x;
  const int l = tid & 63, w = tid >> 6;
  const int row0 = blockIdx.y * 128, col0 = blockIdx.x * 128;
  const int wr = w >> 1, wc = w & 1;

  const unsigned short* Ap0 = A + (size_t)(row0 + w * 32 + (l >> 2)) * K + (l & 3) * 8;
  const unsigned short* Ap1 = Ap0 + (size_t)16 * K;
  const unsigned short* Bp0 = B + (size_t)(col0 + w * 32 + (l >> 2)) * K + (l & 3) * 8;
  const unsigned short* Bp1 = Bp0 + (size_t)16 * K;

  auto ldsA0 = (__attribute__((address_space(3))) void*)(&sA[w * 1024]);
  auto ldsA1 = (__attribute__((address_space(3))) void*)(&sA[w * 1024 + 512]);
  auto ldsB0 = (__attribute__((address_space(3))) void*)(&sB[w * 1024]);
  auto ldsB1 = (__attribute__((address_space(3))) void*)(&sB[w * 1024 + 512]);

  f32x4 acc[4][4] = {};

  const int kq = (l >> 4) * 8;
  const unsigned short* aRd[4];
  const unsigned short* bRd[4];
  #pragma unroll
  for (int m = 0; m < 4; m++) aRd[m] = &sA[(wr * 64 + m * 16 + (l & 15)) * 32 + kq];
  #pragma unroll
  for (int n = 0; n < 4; n++) bRd[n] = &sB[(wc * 64 + n * 16 + (l & 15)) * 32 + kq];

  for (int k0 = 0; k0 < K; k0 += 32){
    __builtin_amdgcn_global_load_lds((const __attribute__((address_space(1))) void*)(Ap0 + k0), ldsA0, 16, 0, 0);
    __builtin_amdgcn_global_load_lds((const __attribute__((address_space(1))) void*)(Ap1 + k0), ldsA1, 16, 0, 0);
    __builtin_amdgcn_global_load_lds((const __attribute__((address_space(1))) void*)(Bp0 + k0), ldsB0, 16, 0, 0);
    __builtin_amdgcn_global_load_lds((const __attribute__((address_space(1))) void*)(Bp1 + k0), ldsB1, 16, 0, 0);
    __syncthreads();
    short8 af[4], bf[4];
    #pragma unroll
    for (int m = 0; m < 4; m++) af[m] = *reinterpret_cast<const short8*>(aRd[m]);
    #pragma unroll
    for (int n = 0; n < 4; n++) bf[n] = *reinterpret_cast<const short8*>(bRd[n]);
    #pragma unroll
    for (int m = 0; m < 4; m++)
      #pragma unroll
      for (int n = 0; n < 4; n++)
        acc[m][n] = __builtin_amdgcn_mfma_f32_16x16x32_bf16(af[m], bf[n], acc[m][n], 0, 0, 0);
    __syncthreads();
  }

  const int orow = row0 + wr * 64 + ((l >> 4) << 2);
  const int ocol = col0 + wc * 64 + (l & 15);
  #pragma unroll
  for (int m = 0; m < 4; m++)
    #pragma unroll
    for (int n = 0; n < 4; n++)
      #pragma unroll
      for (int r = 0; r < 4; r++){
        size_t off = (size_t)(orow + m * 16 + r) * N + (ocol + n * 16);
        if (OUTBF16) ((unsigned short*)Cp)[off] = f2bfu(acc[m][n][r]);
        else         ((float*)Cp)[off] = acc[m][n][r];
      }
}

// ---------------- RoPE (interleaved pairs) on q (softmax scale folded) and k ----------------
__global__ void rope_kernel(const unsigned short* __restrict__ qkv, const float* __restrict__ cosb,
                            const float* __restrict__ sinb, unsigned short* __restrict__ Qo,
                            unsigned short* __restrict__ Ko){
  int idx = blockIdx.x * 256 + threadIdx.x;
  const int NQ = 4096 * 1024;
  if (idx < NQ){
    int m = idx >> 10, p = idx & 1023;
    int h = p >> 5, i = p & 31;
    int s = m & 2047;
    unsigned pr = *reinterpret_cast<const unsigned*>(qkv + (size_t)m * 3072 + h * 64 + 2 * i);
    float t0 = bfu2f((unsigned short)(pr & 0xFFFFu));
    float t1 = bfu2f((unsigned short)(pr >> 16));
    float c = cosb[s * 32 + i], sn = sinb[s * 32 + i];
    const float SC = 0.18033688011112042f;   // (1/8) * log2(e) -> exp2-domain softmax
    float o0 = (t0 * c - t1 * sn) * SC;
    float o1 = (t0 * sn + t1 * c) * SC;
    unsigned ow = (unsigned)f2bfu(o0) | ((unsigned)f2bfu(o1) << 16);
    *reinterpret_cast<unsigned*>(Qo + (size_t)m * 2048 + h * 64 + 2 * i) = ow;
  } else {
    int j = idx - NQ;
    int m = j >> 8, p = j & 255;
    int kvh = p >> 5, i = p & 31;
    int s = m & 2047, b = m >> 11;
    unsigned pr = *reinterpret_cast<const unsigned*>(qkv + (size_t)m * 3072 + 2048 + kvh * 64 + 2 * i);
    float t0 = bfu2f((unsigned short)(pr & 0xFFFFu));
    float t1 = bfu2f((unsigned short)(pr >> 16));
    float c = cosb[s * 32 + i], sn = sinb[s * 32 + i];
    float o0 = t0 * c - t1 * sn;
    float o1 = t0 * sn + t1 * c;
    unsigned ow = (unsigned)f2bfu(o0) | ((unsigned)f2bfu(o1) << 16);
    *reinterpret_cast<unsigned*>(Ko + ((size_t)(b * 8 + kvh) * 2048 + s) * 64 + 2 * i) = ow;
  }
}

// ---------------- V transpose: v_t[b][kvh][d][s] from qkv cols [2560,3072) ----------------
__global__ void vtrans_kernel(const unsigned short* __restrict__ qkv, unsigned short* __restrict__ Vt){
  __shared__ float t[64][65];
  int bh = blockIdx.y;
  int s0 = blockIdx.x * 64;
  int b = bh >> 3, kvh = bh & 7;
  int tid = threadIdx.x;
  #pragma unroll
  for (int it = 0; it < 16; it++){
    int id = it * 256 + tid;
    int sl = id >> 6, d = id & 63;
    unsigned short u = qkv[(size_t)(b * 2048 + s0 + sl) * 3072 + 2560 + kvh * 64 + d];
    t[sl][d] = bfu2f(u);
  }
  __syncthreads();
  #pragma unroll
  for (int it = 0; it < 16; it++){
    int id = it * 256 + tid;
    int dl = id >> 6, sl = id & 63;
    Vt[((size_t)(b * 8 + kvh) * 64 + dl) * 2048 + s0 + sl] = f2bfu(t[sl][dl]);
  }
}

// ---------------- causal GQA flash attention (m214-lite) ----------------
// Q: [4096][2048] bf16 (pre-scaled, exp2 domain). Kt: [b][kvh][s][64]. Vt: [b][kvh][d][s].
// O: [4096][2048] bf16. 4 waves/block x 32 q-rows; K/V staged in swizzled LDS shared by all
// waves; 2-phase prefetch (counted via end-of-tile vmcnt(0) on NEXT tile's loads); swapped
// QK^T (S^T) for in-register softmax rows; P transposed via per-wave swizzled LDS buffer.
__global__ __launch_bounds__(256) void attn_kernel(const unsigned short* __restrict__ Q,
                                                   const unsigned short* __restrict__ Kt,
                                                   const unsigned short* __restrict__ Vt,
                                                   unsigned short* __restrict__ O){
  __shared__ unsigned short sK[2][64 * 64];
  __shared__ unsigned short sV[2][64 * 64];
  __shared__ unsigned short sP[4][32 * 64];
  const int tid = threadIdx.x;
  const int l = tid & 63, w = tid >> 6;
  const int quad = l >> 4, c16 = l & 15;
  const int qt = (int)gridDim.x - 1 - (int)blockIdx.x;   // long blocks dispatch first
  const int bh = blockIdx.y;
  const int b = bh >> 5, h = bh & 31, kvh = h >> 2;
  const int q0w = qt * 128 + w * 32;

  const unsigned short* Kb = Kt + (size_t)(b * 8 + kvh) * 2048 * 64;
  const unsigned short* Vb = Vt + (size_t)(b * 8 + kvh) * 64 * 2048;

  // Q B-frags: 2 q-subtiles x 2 hd-steps (held in registers for the whole kernel)
  short8 qv[2][2];
  #pragma unroll
  for (int qf = 0; qf < 2; qf++){
    const unsigned short* Qp = Q + ((size_t)(b * 2048 + q0w + qf * 16 + c16)) * 2048 + h * 64 + quad * 8;
    qv[qf][0] = *reinterpret_cast<const short8*>(Qp);
    qv[qf][1] = *reinterpret_cast<const short8*>(Qp + 32);
  }

  f32x4 acc[2][4] = {};
  float m_run[2] = {-1e30f, -1e30f};
  float l_run[2] = {0.f, 0.f};
  unsigned short* sPw = &sP[w][0];

  // per-wave staging of its 16 rows of the 64x64 K and V tiles, XOR-swizzled source,
  // linear LDS dest (global_load_lds: wave-uniform base + lane*16)
  auto stage = [&](int kv0, int buf){
    #pragma unroll
    for (int c = 0; c < 2; c++){
      const int rl = w * 16 + c * 8 + (l >> 3);
      const int ce = (((l & 7) ^ (l >> 3)) << 3);
      __builtin_amdgcn_global_load_lds(
        (const __attribute__((address_space(1))) void*)(Kb + (size_t)(kv0 + rl) * 64 + ce),
        (__attribute__((address_space(3))) void*)(&sK[buf][(w * 16 + c * 8) * 64]), 16, 0, 0);
      __builtin_amdgcn_global_load_lds(
        (const __attribute__((address_space(1))) void*)(Vb + (size_t)rl * 2048 + kv0 + ce),
        (__attribute__((address_space(3))) void*)(&sV[buf][(w * 16 + c * 8) * 64]), 16, 0, 0);
    }
  };

  const int nt = qt * 2 + 2;   // uniform trip count for all 4 waves (extra tiles fully masked)

  stage(0, 0);
  asm volatile("s_waitcnt vmcnt(0)" ::: "memory");
  __builtin_amdgcn_s_barrier();

  int buf = 0;
  for (int t = 0; t < nt; ++t){
    const int kv0 = t * 64;
    if (t + 1 < nt) stage((t + 1) * 64, buf ^ 1);   // prefetch: stays in flight across compute

    const unsigned short* sKc = &sK[buf][0];
    const unsigned short* sVc = &sV[buf][0];

    // ---- S^T = K Q^T: z[qf][kb], D[k_local][q]: k = quad*4+r, q = c16 ----
    f32x4 z[2][4];
    #pragma unroll
    for (int kb = 0; kb < 4; kb++){
      const int row = kb * 16 + c16;
      short8 ak0 = *reinterpret_cast<const short8*>(&sKc[swz64(row, quad)]);
      short8 ak1 = *reinterpret_cast<const short8*>(&sKc[swz64(row, 4 + quad)]);
      #pragma unroll
      for (int qf = 0; qf < 2; qf++){
        f32x4 zz = {};
        zz = __builtin_amdgcn_mfma_f32_16x16x32_bf16(ak0, qv[qf][0], zz, 0, 0, 0);
        zz = __builtin_amdgcn_mfma_f32_16x16x32_bf16(ak1, qv[qf][1], zz, 0, 0, 0);
        z[qf][kb] = zz;
      }
    }
    // ---- causal mask (uniform branch; only near-diagonal tiles) ----
    if (kv0 + 63 > q0w){
      #pragma unroll
      for (int qf = 0; qf < 2; qf++){
        const int qg = q0w + qf * 16 + c16;
        #pragma unroll
        for (int kb = 0; kb < 4; kb++)
          #pragma unroll
          for (int r = 0; r < 4; r++){
            const int kg = kv0 + kb * 16 + quad * 4 + r;
            if (kg > qg) z[qf][kb][r] = -1e30f;
          }
      }
    }
    // ---- online softmax: 16 in-register k-values per lane + 2 shfl_xor rounds ----
    #pragma unroll
    for (int qf = 0; qf < 2; qf++){
      float tm = z[qf][0][0];
      #pragma unroll
      for (int kb = 0; kb < 4; kb++)
        #pragma unroll
        for (int r = 0; r < 4; r++) tm = fmaxf(tm, z[qf][kb][r]);
      tm = fmaxf(tm, __shfl_xor(tm, 16));
      tm = fmaxf(tm, __shfl_xor(tm, 32));
      float mn = fmaxf(m_run[qf], tm);
      float al = exp2f(m_run[qf] - mn);
      m_run[qf] = mn;
      float rs = 0.f;
      #pragma unroll
      for (int kb = 0; kb < 4; kb++)
        #pragma unroll
        for (int r = 0; r < 4; r++){
          float p = exp2f(z[qf][kb][r] - mn);
          z[qf][kb][r] = p;
          rs += p;
        }
      rs += __shfl_xor(rs, 16);
      rs += __shfl_xor(rs, 32);
      l_run[qf] = l_run[qf] * al + rs;
      // rescale O accumulator rows (acc row q = quad*4+r needs that row's al)
      #pragma unroll
      for (int r = 0; r < 4; r++){
        float alr = __shfl(al, (quad << 2) | r);
        #pragma unroll
        for (int df = 0; df < 4; df++) acc[qf][df][r] *= alr;
      }
      // ---- write P^T -> per-wave swizzled LDS [32 q][64 k] (packed bf16 pairs) ----
      #pragma unroll
      for (int kb = 0; kb < 4; kb++){
        const int row = qf * 16 + c16;
        const int sl = (kb * 2 + (quad >> 1)) ^ (row & 7);
        unsigned* dst = reinterpret_cast<unsigned*>(&sPw[row * 64 + sl * 8 + (quad & 1) * 4]);
        dst[0] = (unsigned)f2bfu(z[qf][kb][0]) | ((unsigned)f2bfu(z[qf][kb][1]) << 16);
        dst[1] = (unsigned)f2bfu(z[qf][kb][2]) | ((unsigned)f2bfu(z[qf][kb][3]) << 16);
      }
    }
    // ---- P A-frags (transposed back, swizzled read) ----
    short8 ap[2][2];
    #pragma unroll
    for (int qf = 0; qf < 2; qf++){
      const int row = qf * 16 + c16;
      ap[qf][0] = *reinterpret_cast<const short8*>(&sPw[swz64(row, quad)]);
      ap[qf][1] = *reinterpret_cast<const short8*>(&sPw[swz64(row, 4 + quad)]);
    }
    // ---- O += P V ----
    #pragma unroll
    for (int df = 0; df < 4; df++){
      const int row = df * 16 + c16;
      short8 bv0 = *reinterpret_cast<const short8*>(&sVc[swz64(row, quad)]);
      short8 bv1 = *reinterpret_cast<const short8*>(&sVc[swz64(row, 4 + quad)]);
      #pragma unroll
      for (int qf = 0; qf < 2; qf++){
        acc[qf][df] = __builtin_amdgcn_mfma_f32_16x16x32_bf16(ap[qf][0], bv0, acc[qf][df], 0, 0, 0);
        acc[qf][df] = __builtin_amdgcn_mfma_f32_16x16x32_bf16(ap[qf][1], bv1, acc[qf][df], 0, 0, 0);
      }
    }
    // wait only for the prefetch issued this iteration, then flip
    asm volatile("s_waitcnt vmcnt(0)" ::: "memory");
    __builtin_amdgcn_s_barrier();
    buf ^= 1;
  }

  // ---- epilogue: normalize rows and store ----
  #pragma unroll
  for (int qf = 0; qf < 2; qf++)
    #pragma unroll
    for (int r = 0; r < 4; r++){
      float lr = __shfl(l_run[qf], (quad << 2) | r);
      float inv = 1.0f / lr;
      const int qrow = q0w + qf * 16 + quad * 4 + r;
      #pragma unroll
      for (int df = 0; df < 4; df++)
        O[((size_t)(b * 2048 + qrow)) * 2048 + h * 64 + df * 16 + c16] = f2bfu(acc[qf][df][r] * inv);
    }
}

extern "C" void kernel_launch(void* const* d_in, const int* in_sizes, int n_in,
                              void* d_out, int out_size, void* d_ws, size_t ws_size,
                              hipStream_t stream){
  (void)in_sizes; (void)n_in; (void)out_size; (void)ws_size;
  const float* x  = (const float*)d_in[0];
  const float* cb = (const float*)d_in[1];
  const float* sb = (const float*)d_in[2];
  const float* Wq = (const float*)d_in[3];
  const float* Wk = (const float*)d_in[4];
  const float* Wv = (const float*)d_in[5];
  const float* Wo = (const float*)d_in[6];
  float* out = (float*)d_out;
  char* ws = (char*)d_ws;

  unsigned short* qkv = (unsigned short*)(ws + 0);           // [4096][3072] bf16
  unsigned short* xb  = (unsigned short*)(ws + 25165824);    // [4096][2048] bf16; reused as attn-out
  unsigned short* wt  = (unsigned short*)(ws + 41943040);    // WqkvT; later WoT
  unsigned short* qb  = (unsigned short*)(ws + 54525952);    // roped q [4096][2048]
  unsigned short* kb  = (unsigned short*)(ws + 71303168);    // roped k [b][kvh][2048][64]
  unsigned short* vt  = (unsigned short*)(ws + 75497472);    // v^T [b][kvh][64][2048]

  dim3 tb(32, 8);
  convx_kernel<<<8192, 256, 0, stream>>>(x, xb, 2097152);
  transpose_conv_kernel<<<dim3(64, 64), tb, 0, stream>>>(Wq, wt, 2048, 2048);
  transpose_conv_kernel<<<dim3(16, 64), tb, 0, stream>>>(Wk, wt + (size_t)2048 * 2048, 2048, 512);
  transpose_conv_kernel<<<dim3(16, 64), tb, 0, stream>>>(Wv, wt + (size_t)2560 * 2048, 2048, 512);
  gemm_bt_kernel<true><<<dim3(24, 32), 256, 0, stream>>>(xb, wt, qkv, 4096, 3072, 2048);
  rope_kernel<<<20480, 256, 0, stream>>>(qkv, cb, sb, qb, kb);
  vtrans_kernel<<<dim3(32, 16), 256, 0, stream>>>(qkv, vt);
  transpose_conv_kernel<<<dim3(64, 64), tb, 0, stream>>>(Wo, wt, 2048, 2048);  // wt now = WoT
  attn_kernel<<<dim3(16, 64), 256, 0, stream>>>(qb, kb, vt, xb);               // xb now = attn features
  gemm_bt_kernel<false><<<dim3(16, 32), 256, 0, stream>>>(xb, wt, out, 4096, 2048, 2048);
}

// Round 3
// 251.257 us; speedup vs baseline: 2.4371x; 1.3662x over previous
//
#include <hip/hip_runtime.h>
#include <hip/hip_bf16.h>

// Fused attention block: x@Wqkv -> RoPE -> causal GQA flash attention -> @Wo
// bf16 MFMA compute everywhere (2% abs tolerance), f32 I/O.

typedef __attribute__((ext_vector_type(8))) short short8;   // 8 bf16 = 4 VGPR (MFMA A/B frag)
typedef __attribute__((ext_vector_type(4))) float f32x4;    // MFMA C/D frag

__device__ __forceinline__ unsigned short f2bfu(float f){
  unsigned u = __float_as_uint(f);
  u += 0x7FFFu + ((u >> 16) & 1u);      // RNE (no NaNs in this workload)
  return (unsigned short)(u >> 16);
}
__device__ __forceinline__ float bfu2f(unsigned short u){
  return __uint_as_float(((unsigned)u) << 16);
}
// packed f32x2 -> bf16x2 (RNE), single VALU op
__device__ __forceinline__ unsigned cvt_pk_bf16(float lo, float hi){
  unsigned r;
  asm("v_cvt_pk_bf16_f32 %0, %1, %2" : "=v"(r) : "v"(lo), "v"(hi));
  return r;
}
// swizzled element offset in a 64-col bf16 row: slot = 16B unit 0..7, XOR row&7
__device__ __forceinline__ int swz64(int row, int slot){
  return row * 64 + (((slot) ^ (row & 7)) << 3);
}

// ---------------- elementwise f32 -> bf16 ----------------
__global__ void convx_kernel(const float* __restrict__ x, unsigned short* __restrict__ xb, int n4){
  int i = blockIdx.x * blockDim.x + threadIdx.x;
  if (i >= n4) return;
  float4 v = reinterpret_cast<const float4*>(x)[i];
  ushort4 o;
  o.x = f2bfu(v.x); o.y = f2bfu(v.y); o.z = f2bfu(v.z); o.w = f2bfu(v.w);
  reinterpret_cast<ushort4*>(xb)[i] = o;
}

// ---------------- tiled transpose + convert: out[n][k] = (bf16)in[k][n] ----------------
__global__ void transpose_conv_kernel(const float* __restrict__ in, unsigned short* __restrict__ out,
                                      int Min, int Nin){
  __shared__ float t[32][33];
  int c0 = blockIdx.x * 32, r0 = blockIdx.y * 32;
  int tx = threadIdx.x, ty = threadIdx.y;   // 32 x 8
  #pragma unroll
  for (int i = ty; i < 32; i += 8) t[i][tx] = in[(size_t)(r0 + i) * Nin + c0 + tx];
  __syncthreads();
  #pragma unroll
  for (int i = ty; i < 32; i += 8) out[(size_t)(c0 + i) * Min + r0 + tx] = f2bfu(t[tx][i]);
}

// ---------------- m97-style bf16 GEMM: C[M][N] = A[M][K] * B^T[N][K] ----------------
template<bool OUTBF16>
__global__ __launch_bounds__(256) void gemm_bt_kernel(const unsigned short* __restrict__ A,
                                                      const unsigned short* __restrict__ B,
                                                      void* __restrict__ Cp,
                                                      int M, int N, int K){
  __shared__ unsigned short sA[128 * 32];
  __shared__ unsigned short sB[128 * 32];
  const int tid = threadIdx.x;
  const int l = tid & 63, w = tid >> 6;
  const int row0 = blockIdx.y * 128, col0 = blockIdx.x * 128;
  const int wr = w >> 1, wc = w & 1;

  const unsigned short* Ap0 = A + (size_t)(row0 + w * 32 + (l >> 2)) * K + (l & 3) * 8;
  const unsigned short* Ap1 = Ap0 + (size_t)16 * K;
  const unsigned short* Bp0 = B + (size_t)(col0 + w * 32 + (l >> 2)) * K + (l & 3) * 8;
  const unsigned short* Bp1 = Bp0 + (size_t)16 * K;

  auto ldsA0 = (__attribute__((address_space(3))) void*)(&sA[w * 1024]);
  auto ldsA1 = (__attribute__((address_space(3))) void*)(&sA[w * 1024 + 512]);
  auto ldsB0 = (__attribute__((address_space(3))) void*)(&sB[w * 1024]);
  auto ldsB1 = (__attribute__((address_space(3))) void*)(&sB[w * 1024 + 512]);

  f32x4 acc[4][4] = {};

  const int kq = (l >> 4) * 8;
  const unsigned short* aRd[4];
  const unsigned short* bRd[4];
  #pragma unroll
  for (int m = 0; m < 4; m++) aRd[m] = &sA[(wr * 64 + m * 16 + (l & 15)) * 32 + kq];
  #pragma unroll
  for (int n = 0; n < 4; n++) bRd[n] = &sB[(wc * 64 + n * 16 + (l & 15)) * 32 + kq];

  for (int k0 = 0; k0 < K; k0 += 32){
    __builtin_amdgcn_global_load_lds((const __attribute__((address_space(1))) void*)(Ap0 + k0), ldsA0, 16, 0, 0);
    __builtin_amdgcn_global_load_lds((const __attribute__((address_space(1))) void*)(Ap1 + k0), ldsA1, 16, 0, 0);
    __builtin_amdgcn_global_load_lds((const __attribute__((address_space(1))) void*)(Bp0 + k0), ldsB0, 16, 0, 0);
    __builtin_amdgcn_global_load_lds((const __attribute__((address_space(1))) void*)(Bp1 + k0), ldsB1, 16, 0, 0);
    __syncthreads();
    short8 af[4], bf[4];
    #pragma unroll
    for (int m = 0; m < 4; m++) af[m] = *reinterpret_cast<const short8*>(aRd[m]);
    #pragma unroll
    for (int n = 0; n < 4; n++) bf[n] = *reinterpret_cast<const short8*>(bRd[n]);
    #pragma unroll
    for (int m = 0; m < 4; m++)
      #pragma unroll
      for (int n = 0; n < 4; n++)
        acc[m][n] = __builtin_amdgcn_mfma_f32_16x16x32_bf16(af[m], bf[n], acc[m][n], 0, 0, 0);
    __syncthreads();
  }

  const int orow = row0 + wr * 64 + ((l >> 4) << 2);
  const int ocol = col0 + wc * 64 + (l & 15);
  #pragma unroll
  for (int m = 0; m < 4; m++)
    #pragma unroll
    for (int n = 0; n < 4; n++)
      #pragma unroll
      for (int r = 0; r < 4; r++){
        size_t off = (size_t)(orow + m * 16 + r) * N + (ocol + n * 16);
        if (OUTBF16) ((unsigned short*)Cp)[off] = f2bfu(acc[m][n][r]);
        else         ((float*)Cp)[off] = acc[m][n][r];
      }
}

// ---------------- RoPE (interleaved pairs) on q (softmax scale folded) and k ----------------
__global__ void rope_kernel(const unsigned short* __restrict__ qkv, const float* __restrict__ cosb,
                            const float* __restrict__ sinb, unsigned short* __restrict__ Qo,
                            unsigned short* __restrict__ Ko){
  int idx = blockIdx.x * 256 + threadIdx.x;
  const int NQ = 4096 * 1024;
  if (idx < NQ){
    int m = idx >> 10, p = idx & 1023;
    int h = p >> 5, i = p & 31;
    int s = m & 2047;
    unsigned pr = *reinterpret_cast<const unsigned*>(qkv + (size_t)m * 3072 + h * 64 + 2 * i);
    float t0 = bfu2f((unsigned short)(pr & 0xFFFFu));
    float t1 = bfu2f((unsigned short)(pr >> 16));
    float c = cosb[s * 32 + i], sn = sinb[s * 32 + i];
    const float SC = 0.18033688011112042f;   // (1/8) * log2(e) -> exp2-domain softmax
    float o0 = (t0 * c - t1 * sn) * SC;
    float o1 = (t0 * sn + t1 * c) * SC;
    unsigned ow = (unsigned)f2bfu(o0) | ((unsigned)f2bfu(o1) << 16);
    *reinterpret_cast<unsigned*>(Qo + (size_t)m * 2048 + h * 64 + 2 * i) = ow;
  } else {
    int j = idx - NQ;
    int m = j >> 8, p = j & 255;
    int kvh = p >> 5, i = p & 31;
    int s = m & 2047, b = m >> 11;
    unsigned pr = *reinterpret_cast<const unsigned*>(qkv + (size_t)m * 3072 + 2048 + kvh * 64 + 2 * i);
    float t0 = bfu2f((unsigned short)(pr & 0xFFFFu));
    float t1 = bfu2f((unsigned short)(pr >> 16));
    float c = cosb[s * 32 + i], sn = sinb[s * 32 + i];
    float o0 = t0 * c - t1 * sn;
    float o1 = t0 * sn + t1 * c;
    unsigned ow = (unsigned)f2bfu(o0) | ((unsigned)f2bfu(o1) << 16);
    *reinterpret_cast<unsigned*>(Ko + ((size_t)(b * 8 + kvh) * 2048 + s) * 64 + 2 * i) = ow;
  }
}

// ---------------- V transpose: v_t[b][kvh][d][s] from qkv cols [2560,3072) ----------------
__global__ void vtrans_kernel(const unsigned short* __restrict__ qkv, unsigned short* __restrict__ Vt){
  __shared__ float t[64][65];
  int bh = blockIdx.y;
  int s0 = blockIdx.x * 64;
  int b = bh >> 3, kvh = bh & 7;
  int tid = threadIdx.x;
  #pragma unroll
  for (int it = 0; it < 16; it++){
    int id = it * 256 + tid;
    int sl = id >> 6, d = id & 63;
    unsigned short u = qkv[(size_t)(b * 2048 + s0 + sl) * 3072 + 2560 + kvh * 64 + d];
    t[sl][d] = bfu2f(u);
  }
  __syncthreads();
  #pragma unroll
  for (int it = 0; it < 16; it++){
    int id = it * 256 + tid;
    int dl = id >> 6, sl = id & 63;
    Vt[((size_t)(b * 8 + kvh) * 64 + dl) * 2048 + s0 + sl] = f2bfu(t[sl][dl]);
  }
}

// ---------------- causal GQA flash attention ----------------
// Q: [4096][2048] bf16 (pre-scaled, exp2 domain). Kt: [b][kvh][s][64]. Vt: [b][kvh][d][s].
// O: [4096][2048] bf16.
// Grid (64 bh, 8 px): block processes q-tiles qt=px and qt=15-px -> uniform 36 kv-tiles/block.
// 4 waves x 32 q-rows; K/V in swizzled double-buffered LDS; swapped QK^T; defer-max (THR=8);
// cvt_pk P-pack; setprio around MFMA clusters.
__global__ __launch_bounds__(256) void attn_kernel(const unsigned short* __restrict__ Q,
                                                   const unsigned short* __restrict__ Kt,
                                                   const unsigned short* __restrict__ Vt,
                                                   unsigned short* __restrict__ O){
  __shared__ unsigned short sK[2][64 * 64];
  __shared__ unsigned short sV[2][64 * 64];
  __shared__ unsigned short sP[4][32 * 64];
  const int tid = threadIdx.x;
  const int l = tid & 63, w = tid >> 6;
  const int quad = l >> 4, c16 = l & 15;
  const int bh = blockIdx.x;              // same-K/V blocks land on same XCD (flat%8)
  const int px = blockIdx.y;              // 0..7 -> q-tile pair {px, 15-px}
  const int b = bh >> 5, h = bh & 31, kvh = h >> 2;

  const unsigned short* Kb = Kt + (size_t)(b * 8 + kvh) * 2048 * 64;
  const unsigned short* Vb = Vt + (size_t)(b * 8 + kvh) * 64 * 2048;
  unsigned short* sPw = &sP[w][0];

  auto stage = [&](int kv0, int buf){
    #pragma unroll
    for (int c = 0; c < 2; c++){
      const int rl = w * 16 + c * 8 + (l >> 3);
      const int ce = (((l & 7) ^ (l >> 3)) << 3);
      __builtin_amdgcn_global_load_lds(
        (const __attribute__((address_space(1))) void*)(Kb + (size_t)(kv0 + rl) * 64 + ce),
        (__attribute__((address_space(3))) void*)(&sK[buf][(w * 16 + c * 8) * 64]), 16, 0, 0);
      __builtin_amdgcn_global_load_lds(
        (const __attribute__((address_space(1))) void*)(Vb + (size_t)rl * 2048 + kv0 + ce),
        (__attribute__((address_space(3))) void*)(&sV[buf][(w * 16 + c * 8) * 64]), 16, 0, 0);
    }
  };

  int buf = 0;
  #pragma unroll 1
  for (int phase = 0; phase < 2; ++phase){
    const int qt = phase ? (15 - px) : px;
    const int q0w = qt * 128 + w * 32;
    const int nt = 2 * qt + 2;   // uniform across the block's 4 waves

    // Q B-frags for this q-tile
    short8 qv[2][2];
    #pragma unroll
    for (int qf = 0; qf < 2; qf++){
      const unsigned short* Qp = Q + ((size_t)(b * 2048 + q0w + qf * 16 + c16)) * 2048 + h * 64 + quad * 8;
      qv[qf][0] = *reinterpret_cast<const short8*>(Qp);
      qv[qf][1] = *reinterpret_cast<const short8*>(Qp + 32);
    }

    f32x4 acc[2][4] = {};
    float m_run[2] = {-1e30f, -1e30f};
    float l_run[2] = {0.f, 0.f};

    stage(0, buf);
    asm volatile("s_waitcnt vmcnt(0)" ::: "memory");
    __builtin_amdgcn_s_barrier();

    for (int t = 0; t < nt; ++t){
      const int kv0 = t * 64;
      if (t + 1 < nt) stage((t + 1) * 64, buf ^ 1);   // prefetch stays in flight over compute

      const unsigned short* sKc = &sK[buf][0];
      const unsigned short* sVc = &sV[buf][0];

      // ---- S^T = K Q^T: D[k_local][q]: k = quad*4+r, q = c16 ----
      f32x4 z[2][4];
      __builtin_amdgcn_s_setprio(1);
      #pragma unroll
      for (int kb = 0; kb < 4; kb++){
        const int row = kb * 16 + c16;
        short8 ak0 = *reinterpret_cast<const short8*>(&sKc[swz64(row, quad)]);
        short8 ak1 = *reinterpret_cast<const short8*>(&sKc[swz64(row, 4 + quad)]);
        #pragma unroll
        for (int qf = 0; qf < 2; qf++){
          f32x4 zz = {};
          zz = __builtin_amdgcn_mfma_f32_16x16x32_bf16(ak0, qv[qf][0], zz, 0, 0, 0);
          zz = __builtin_amdgcn_mfma_f32_16x16x32_bf16(ak1, qv[qf][1], zz, 0, 0, 0);
          z[qf][kb] = zz;
        }
      }
      __builtin_amdgcn_s_setprio(0);

      // ---- causal mask (wave-uniform branch; only near-diagonal tiles) ----
      if (kv0 + 63 > q0w){
        #pragma unroll
        for (int qf = 0; qf < 2; qf++){
          const int qg = q0w + qf * 16 + c16;
          #pragma unroll
          for (int kb = 0; kb < 4; kb++)
            #pragma unroll
            for (int r = 0; r < 4; r++){
              const int kg = kv0 + kb * 16 + quad * 4 + r;
              if (kg > qg) z[qf][kb][r] = -1e30f;
            }
        }
      }

      // ---- online softmax with defer-max (THR=8 in log2 domain) ----
      #pragma unroll
      for (int qf = 0; qf < 2; qf++){
        float tm = z[qf][0][0];
        #pragma unroll
        for (int kb = 0; kb < 4; kb++)
          #pragma unroll
          for (int r = 0; r < 4; r++) tm = fmaxf(tm, z[qf][kb][r]);
        tm = fmaxf(tm, __shfl_xor(tm, 16));
        tm = fmaxf(tm, __shfl_xor(tm, 32));
        if (!__all(tm <= m_run[qf] + 8.0f)){      // rare: real max growth
          float mn = fmaxf(m_run[qf], tm);
          float al = exp2f(m_run[qf] - mn);
          m_run[qf] = mn;
          l_run[qf] *= al;
          #pragma unroll
          for (int r = 0; r < 4; r++){
            float alr = __shfl(al, (quad << 2) | r);
            #pragma unroll
            for (int df = 0; df < 4; df++) acc[qf][df][r] *= alr;
          }
        }
        float rs = 0.f;
        #pragma unroll
        for (int kb = 0; kb < 4; kb++)
          #pragma unroll
          for (int r = 0; r < 4; r++){
            float p = exp2f(z[qf][kb][r] - m_run[qf]);
            z[qf][kb][r] = p;
            rs += p;
          }
        rs += __shfl_xor(rs, 16);
        rs += __shfl_xor(rs, 32);
        l_run[qf] += rs;
        // ---- write P^T -> per-wave swizzled LDS (packed via v_cvt_pk_bf16_f32) ----
        #pragma unroll
        for (int kb = 0; kb < 4; kb++){
          const int row = qf * 16 + c16;
          const int sl = (kb * 2 + (quad >> 1)) ^ (row & 7);
          unsigned* dst = reinterpret_cast<unsigned*>(&sPw[row * 64 + sl * 8 + (quad & 1) * 4]);
          dst[0] = cvt_pk_bf16(z[qf][kb][0], z[qf][kb][1]);
          dst[1] = cvt_pk_bf16(z[qf][kb][2], z[qf][kb][3]);
        }
      }

      // ---- P A-frags (transposed back, swizzled read) ----
      short8 ap[2][2];
      #pragma unroll
      for (int qf = 0; qf < 2; qf++){
        const int row = qf * 16 + c16;
        ap[qf][0] = *reinterpret_cast<const short8*>(&sPw[swz64(row, quad)]);
        ap[qf][1] = *reinterpret_cast<const short8*>(&sPw[swz64(row, 4 + quad)]);
      }
      // ---- O += P V ----
      __builtin_amdgcn_s_setprio(1);
      #pragma unroll
      for (int df = 0; df < 4; df++){
        const int row = df * 16 + c16;
        short8 bv0 = *reinterpret_cast<const short8*>(&sVc[swz64(row, quad)]);
        short8 bv1 = *reinterpret_cast<const short8*>(&sVc[swz64(row, 4 + quad)]);
        #pragma unroll
        for (int qf = 0; qf < 2; qf++){
          acc[qf][df] = __builtin_amdgcn_mfma_f32_16x16x32_bf16(ap[qf][0], bv0, acc[qf][df], 0, 0, 0);
          acc[qf][df] = __builtin_amdgcn_mfma_f32_16x16x32_bf16(ap[qf][1], bv1, acc[qf][df], 0, 0, 0);
        }
      }
      __builtin_amdgcn_s_setprio(0);

      asm volatile("s_waitcnt vmcnt(0)" ::: "memory");
      __builtin_amdgcn_s_barrier();
      buf ^= 1;
    }

    // ---- epilogue: normalize rows and store ----
    #pragma unroll
    for (int qf = 0; qf < 2; qf++)
      #pragma unroll
      for (int r = 0; r < 4; r++){
        float lr = __shfl(l_run[qf], (quad << 2) | r);
        float inv = 1.0f / lr;
        const int qrow = q0w + qf * 16 + quad * 4 + r;
        #pragma unroll
        for (int df = 0; df < 4; df++)
          O[((size_t)(b * 2048 + qrow)) * 2048 + h * 64 + df * 16 + c16] = f2bfu(acc[qf][df][r] * inv);
      }
  }
}

extern "C" void kernel_launch(void* const* d_in, const int* in_sizes, int n_in,
                              void* d_out, int out_size, void* d_ws, size_t ws_size,
                              hipStream_t stream){
  (void)in_sizes; (void)n_in; (void)out_size; (void)ws_size;
  const float* x  = (const float*)d_in[0];
  const float* cb = (const float*)d_in[1];
  const float* sb = (const float*)d_in[2];
  const float* Wq = (const float*)d_in[3];
  const float* Wk = (const float*)d_in[4];
  const float* Wv = (const float*)d_in[5];
  const float* Wo = (const float*)d_in[6];
  float* out = (float*)d_out;
  char* ws = (char*)d_ws;

  unsigned short* qkv = (unsigned short*)(ws + 0);           // [4096][3072] bf16
  unsigned short* xb  = (unsigned short*)(ws + 25165824);    // [4096][2048] bf16; reused as attn-out
  unsigned short* wt  = (unsigned short*)(ws + 41943040);    // WqkvT; later WoT
  unsigned short* qb  = (unsigned short*)(ws + 54525952);    // roped q [4096][2048]
  unsigned short* kb  = (unsigned short*)(ws + 71303168);    // roped k [b][kvh][2048][64]
  unsigned short* vt  = (unsigned short*)(ws + 75497472);    // v^T [b][kvh][64][2048]

  dim3 tb(32, 8);
  convx_kernel<<<8192, 256, 0, stream>>>(x, xb, 2097152);
  transpose_conv_kernel<<<dim3(64, 64), tb, 0, stream>>>(Wq, wt, 2048, 2048);
  transpose_conv_kernel<<<dim3(16, 64), tb, 0, stream>>>(Wk, wt + (size_t)2048 * 2048, 2048, 512);
  transpose_conv_kernel<<<dim3(16, 64), tb, 0, stream>>>(Wv, wt + (size_t)2560 * 2048, 2048, 512);
  gemm_bt_kernel<true><<<dim3(24, 32), 256, 0, stream>>>(xb, wt, qkv, 4096, 3072, 2048);
  rope_kernel<<<20480, 256, 0, stream>>>(qkv, cb, sb, qb, kb);
  vtrans_kernel<<<dim3(32, 16), 256, 0, stream>>>(qkv, vt);
  transpose_conv_kernel<<<dim3(64, 64), tb, 0, stream>>>(Wo, wt, 2048, 2048);  // wt now = WoT
  attn_kernel<<<dim3(64, 8), 256, 0, stream>>>(qb, kb, vt, xb);                // xb now = attn features
  gemm_bt_kernel<false><<<dim3(16, 32), 256, 0, stream>>>(xb, wt, out, 4096, 2048, 2048);
}